// Round 5
// baseline (150.111 us; speedup 1.0000x reference)
//
#include <hip/hip_runtime.h>
#include <stdint.h>

#define HASH_MASK 524287u        // HASHMAP_SIZE - 1
#define PRIME1 2654435761u
#define PRIME2 805459861u
#define RES 128.0f

typedef float f4 __attribute__((ext_vector_type(4)));
typedef float f2 __attribute__((ext_vector_type(2)));

// wait until at most N vmem ops outstanding, then hard scheduling fence so
// consumers cannot hoist above the wait (rule: asm waitcnt alone is hoistable)
#define WAITV_(N) asm volatile("s_waitcnt vmcnt(" #N ")" ::: "memory")
#define WAITV(N) do { WAITV_(N); __builtin_amdgcn_sched_barrier(0); } while (0)

// hash one point -> 8 byte offsets into emb (float2 entries) + 3 fracs
__device__ __forceinline__ void hash_point(float X, float Y, float Z,
                                           uint32_t* o, float* fr) {
    float fx = X * RES, fy = Y * RES, fz = Z * RES;
    float flx = floorf(fx), fly = floorf(fy), flz = floorf(fz);
    int ix = (int)flx, iy = (int)fly, iz = (int)flz;
    fr[0] = fx - flx; fr[1] = fy - fly; fr[2] = fz - flz;
    uint32_t h0a = (uint32_t)ix,          h0b = h0a + 1u;
    uint32_t h1a = (uint32_t)iy * PRIME1, h1b = h1a + PRIME1;
    uint32_t h2a = (uint32_t)iz * PRIME2, h2b = h2a + PRIME2;
    #pragma unroll
    for (int n = 0; n < 8; ++n) {
        // bit d of n clear -> lower index in dim d (matches BIN_MASK)
        uint32_t h = ((n & 1) ? h0b : h0a)
                   ^ ((n & 2) ? h1b : h1a)
                   ^ ((n & 4) ? h2b : h2a);
        o[n] = (h & HASH_MASK) << 3;     // float2 = 8 bytes
    }
}

// hash a 2-point group (x layout: [p0.x p0.y][p0.z p1.x][p1.y p1.z]) and
// issue its 16 gathers (asm: issue order fixed, results forced live)
__device__ __forceinline__ void hash_issue(f2 X0, f2 X1, f2 X2,
                                           float* fr, f2* e,
                                           const float* emb) {
    uint32_t o[16];
    hash_point(X0.x, X0.y, X1.x, o + 0, fr + 0);
    hash_point(X1.y, X2.x, X2.y, o + 8, fr + 3);
    #pragma unroll
    for (int n = 0; n < 16; ++n)
        asm volatile("global_load_dwordx2 %0, %1, %2"
                     : "=v"(e[n]) : "v"(o[n]), "s"(emb));
}

// issue the 3 coalesced 8B x-loads of one group (6 floats)
__device__ __forceinline__ void xload(f2& a, f2& b, f2& c,
                                      uint32_t voff, const float* xp) {
    asm volatile("global_load_dwordx2 %0, %1, %2"           : "=v"(a) : "v"(voff), "s"(xp));
    asm volatile("global_load_dwordx2 %0, %1, %2 offset:8"  : "=v"(b) : "v"(voff), "s"(xp));
    asm volatile("global_load_dwordx2 %0, %1, %2 offset:16" : "=v"(c) : "v"(voff), "s"(xp));
}

// trilinear weights + accumulate one 2-point group -> packed float4
__device__ __forceinline__ void consume2(const f2* e, const float* fr, f4& o) {
    float acc0 = 0.f, acc1 = 0.f, acc2 = 0.f, acc3 = 0.f;
    {
        float wxa = 1.f - fr[0], wxb = fr[0];
        float wya = 1.f - fr[1], wyb = fr[1];
        float wza = 1.f - fr[2], wzb = fr[2];
        #pragma unroll
        for (int n = 0; n < 8; ++n) {
            float w = (((n & 1) ? wxb : wxa) * ((n & 2) ? wyb : wya))
                      * ((n & 4) ? wzb : wza);
            acc0 = fmaf(e[n].x, w, acc0);
            acc1 = fmaf(e[n].y, w, acc1);
        }
    }
    {
        float wxa = 1.f - fr[3], wxb = fr[3];
        float wya = 1.f - fr[4], wyb = fr[4];
        float wza = 1.f - fr[5], wzb = fr[5];
        #pragma unroll
        for (int n = 0; n < 8; ++n) {
            float w = (((n & 1) ? wxb : wxa) * ((n & 2) ? wyb : wya))
                      * ((n & 4) ? wzb : wza);
            acc2 = fmaf(e[8 + n].x, w, acc2);
            acc3 = fmaf(e[8 + n].y, w, acc3);
        }
    }
    o = (f4){acc0, acc1, acc2, acc3};
}

__device__ __forceinline__ void store4(uint32_t voff, float* op, f4 v) {
    asm volatile("global_store_dwordx4 %0, %1, %2"
                 :: "v"(voff), "v"(v), "s"(op) : "memory");
}

// 16 points per thread = 8 groups of 2; rolling depth-2 pipeline.
// Exact vmcnt ledger (issue order):
//  P: g0, x2, g1, x3 | b0: st0,g2,x4 | b1: st1,g3,x5 | b2: st2,g4,x6
//  b3: st3,g5,x7 | b4: st4,g6 | b5: st5,g7 | b6: st6 | b7: st7
__global__ __launch_bounds__(256, 4) void hashgrid_fwd(
    const float* __restrict__ x,
    const float* __restrict__ emb,
    float* __restrict__ out,
    int nthreads)
{
    int t = blockIdx.x * blockDim.x + threadIdx.x;
    if (t >= nthreads) return;

    uint32_t vx = (uint32_t)t * 192u;   // 16 points * 12 B
    uint32_t vo = (uint32_t)t * 128u;   // 16 points * 8 B out

    f2 xA0, xA1, xA2, xB0, xB1, xB2;
    f2 eA[16], eB[16];
    float frA[6], frB[6];
    f4 sv;

    // ---- prologue: fill pipeline ----
    xload(xA0, xA1, xA2, vx + 0,  x);            // x(0)
    xload(xB0, xB1, xB2, vx + 24, x);            // x(1)
    WAITV(0);
    hash_issue(xA0, xA1, xA2, frA, eA, emb);     // g0
    xload(xA0, xA1, xA2, vx + 48, x);            // x2
    hash_issue(xB0, xB1, xB2, frB, eB, emb);     // g1
    xload(xB0, xB1, xB2, vx + 72, x);            // x3
    // outstanding: g0(16), x2(3), g1(16), x3(3)

    // ---- body 0 (set A) ----
    WAITV(22);                                   // g0 done (x2+g1+x3=22 newer)
    consume2(eA, frA, sv);
    store4(vo + 0, out, sv);                     // st0
    WAITV(20);                                   // x2 done (g1+x3+st0=20 newer)
    hash_issue(xA0, xA1, xA2, frA, eA, emb);     // g2
    xload(xA0, xA1, xA2, vx + 96, x);            // x4

    // ---- body 1 (set B) ----
    WAITV(23);                                   // g1 done (x3+st0+g2+x4)
    consume2(eB, frB, sv);
    store4(vo + 16, out, sv);                    // st1
    WAITV(21);                                   // x3 done (st0+g2+x4+st1)
    hash_issue(xB0, xB1, xB2, frB, eB, emb);     // g3
    xload(xB0, xB1, xB2, vx + 120, x);           // x5

    // ---- body 2 (set A) ----
    WAITV(23);                                   // g2 done (x4+st1+g3+x5)
    consume2(eA, frA, sv);
    store4(vo + 32, out, sv);                    // st2
    WAITV(21);                                   // x4 done (st1+g3+x5+st2)
    hash_issue(xA0, xA1, xA2, frA, eA, emb);     // g4
    xload(xA0, xA1, xA2, vx + 144, x);           // x6

    // ---- body 3 (set B) ----
    WAITV(23);                                   // g3 done (x5+st2+g4+x6)
    consume2(eB, frB, sv);
    store4(vo + 48, out, sv);                    // st3
    WAITV(21);                                   // x5 done (st2+g4+x6+st3)
    hash_issue(xB0, xB1, xB2, frB, eB, emb);     // g5
    xload(xB0, xB1, xB2, vx + 168, x);           // x7

    // ---- body 4 (set A) ----
    WAITV(23);                                   // g4 done (x6+st3+g5+x7)
    consume2(eA, frA, sv);
    store4(vo + 64, out, sv);                    // st4
    WAITV(21);                                   // x6 done (st3+g5+x7+st4)
    hash_issue(xA0, xA1, xA2, frA, eA, emb);     // g6 (no x prefetch)

    // ---- body 5 (set B) ----
    WAITV(20);                                   // g5 done (x7+st4+g6)
    consume2(eB, frB, sv);
    store4(vo + 80, out, sv);                    // st5
    WAITV(18);                                   // x7 done (st4+g6+st5)
    hash_issue(xB0, xB1, xB2, frB, eB, emb);     // g7

    // ---- body 6 (set A) ----
    WAITV(17);                                   // g6 done (st5+g7)
    consume2(eA, frA, sv);
    store4(vo + 96, out, sv);                    // st6

    // ---- body 7 (set B) ----
    WAITV(1);                                    // g7 done (st6)
    consume2(eB, frB, sv);
    store4(vo + 112, out, sv);                   // st7
}

// safety net for npts % 16 != 0 (not hit at N=4M)
__global__ void hashgrid_tail(const float* __restrict__ x,
                              const float* __restrict__ emb,
                              float* __restrict__ out,
                              int start, int npts)
{
    int p = start + blockIdx.x * blockDim.x + threadIdx.x;
    if (p >= npts) return;
    uint32_t o[8]; float fr[3];
    hash_point(x[3 * p], x[3 * p + 1], x[3 * p + 2], o, fr);
    const f2* ev = reinterpret_cast<const f2*>(emb);
    float wxa = 1.f - fr[0], wxb = fr[0];
    float wya = 1.f - fr[1], wyb = fr[1];
    float wza = 1.f - fr[2], wzb = fr[2];
    float s0 = 0.f, s1 = 0.f;
    #pragma unroll
    for (int n = 0; n < 8; ++n) {
        float w = (((n & 1) ? wxb : wxa) * ((n & 2) ? wyb : wya))
                  * ((n & 4) ? wzb : wza);
        f2 e = ev[o[n] >> 3];
        s0 = fmaf(e.x, w, s0);
        s1 = fmaf(e.y, w, s1);
    }
    out[2 * p]     = s0;
    out[2 * p + 1] = s1;
}

extern "C" void kernel_launch(void* const* d_in, const int* in_sizes, int n_in,
                              void* d_out, int out_size, void* d_ws, size_t ws_size,
                              hipStream_t stream) {
    const float* x   = (const float*)d_in[0];   // N*3
    const float* emb = (const float*)d_in[1];   // H*2
    float* out = (float*)d_out;                 // N*2

    int npts = in_sizes[0] / 3;                 // 4,000,000
    int nthreads = npts / 16;                   // 250,000 threads, 16 pts each
    int block = 256;
    int grid = (nthreads + block - 1) / block;  // 977

    hashgrid_fwd<<<grid, block, 0, stream>>>(x, emb, out, nthreads);

    int done = nthreads * 16;
    int rem = npts - done;
    if (rem > 0) {
        int tg = (rem + 255) / 256;
        hashgrid_tail<<<tg, 256, 0, stream>>>(x, emb, out, done, npts);
    }
}

// Round 6
// 104.470 us; speedup vs baseline: 1.4369x; 1.4369x over previous
//
#include <hip/hip_runtime.h>
#include <stdint.h>

#define HASH_MASK 524287u        // HASHMAP_SIZE - 1
#define PRIME1 2654435761u
#define PRIME2 805459861u
#define RES 128.0f

typedef float f4 __attribute__((ext_vector_type(4)));
typedef float f2 __attribute__((ext_vector_type(2)));

// wait until at most N vmem ops outstanding, then hard scheduling fence so
// consumers cannot hoist above the wait (rule: asm waitcnt alone is hoistable)
#define WAITV_(N) asm volatile("s_waitcnt vmcnt(" #N ")" ::: "memory")
#define WAITV(N) do { WAITV_(N); __builtin_amdgcn_sched_barrier(0); } while (0)

// hash one point -> 8 byte offsets into emb (float2 entries) + 3 fracs
__device__ __forceinline__ void hash_point(float X, float Y, float Z,
                                           uint32_t* o, float* fr) {
    float fx = X * RES, fy = Y * RES, fz = Z * RES;
    float flx = floorf(fx), fly = floorf(fy), flz = floorf(fz);
    int ix = (int)flx, iy = (int)fly, iz = (int)flz;
    fr[0] = fx - flx; fr[1] = fy - fly; fr[2] = fz - flz;
    uint32_t h0a = (uint32_t)ix,          h0b = h0a + 1u;
    uint32_t h1a = (uint32_t)iy * PRIME1, h1b = h1a + PRIME1;
    uint32_t h2a = (uint32_t)iz * PRIME2, h2b = h2a + PRIME2;
    #pragma unroll
    for (int n = 0; n < 8; ++n) {
        // bit d of n clear -> lower index in dim d (matches BIN_MASK)
        uint32_t h = ((n & 1) ? h0b : h0a)
                   ^ ((n & 2) ? h1b : h1a)
                   ^ ((n & 4) ? h2b : h2a);
        o[n] = (h & HASH_MASK) << 3;     // float2 = 8 bytes
    }
}

// hash a 2-point group (x layout: [p0.x p0.y][p0.z p1.x][p1.y p1.z]) and
// issue its 16 gathers (asm: issue order fixed, results forced live)
__device__ __forceinline__ void hash_issue(f2 X0, f2 X1, f2 X2,
                                           float* fr, f2* e,
                                           const float* emb) {
    uint32_t o[16];
    hash_point(X0.x, X0.y, X1.x, o + 0, fr + 0);
    hash_point(X1.y, X2.x, X2.y, o + 8, fr + 3);
    #pragma unroll
    for (int n = 0; n < 16; ++n)
        asm volatile("global_load_dwordx2 %0, %1, %2"
                     : "=v"(e[n]) : "v"(o[n]), "s"(emb));
}

// issue the 3 coalesced 8B x-loads of one pair (6 floats, lane stride 24B:
// wave covers a dense contiguous 1536B region -> every line fully used)
__device__ __forceinline__ void xload(f2& a, f2& b, f2& c,
                                      uint32_t voff, const float* xp) {
    asm volatile("global_load_dwordx2 %0, %1, %2"           : "=v"(a) : "v"(voff), "s"(xp));
    asm volatile("global_load_dwordx2 %0, %1, %2 offset:8"  : "=v"(b) : "v"(voff), "s"(xp));
    asm volatile("global_load_dwordx2 %0, %1, %2 offset:16" : "=v"(c) : "v"(voff), "s"(xp));
}

// trilinear weights + accumulate one 2-point group -> packed float4
__device__ __forceinline__ void consume2(const f2* e, const float* fr, f4& o) {
    float acc0 = 0.f, acc1 = 0.f, acc2 = 0.f, acc3 = 0.f;
    {
        float wxa = 1.f - fr[0], wxb = fr[0];
        float wya = 1.f - fr[1], wyb = fr[1];
        float wza = 1.f - fr[2], wzb = fr[2];
        #pragma unroll
        for (int n = 0; n < 8; ++n) {
            float w = (((n & 1) ? wxb : wxa) * ((n & 2) ? wyb : wya))
                      * ((n & 4) ? wzb : wza);
            acc0 = fmaf(e[n].x, w, acc0);
            acc1 = fmaf(e[n].y, w, acc1);
        }
    }
    {
        float wxa = 1.f - fr[3], wxb = fr[3];
        float wya = 1.f - fr[4], wyb = fr[4];
        float wza = 1.f - fr[5], wzb = fr[5];
        #pragma unroll
        for (int n = 0; n < 8; ++n) {
            float w = (((n & 1) ? wxb : wxa) * ((n & 2) ? wyb : wya))
                      * ((n & 4) ? wzb : wza);
            acc2 = fmaf(e[8 + n].x, w, acc2);
            acc3 = fmaf(e[8 + n].y, w, acc3);
        }
    }
    o = (f4){acc0, acc1, acc2, acc3};
}

__device__ __forceinline__ void store4(uint32_t voff, float* op, f4 v) {
    asm volatile("global_store_dwordx4 %0, %1, %2"
                 :: "v"(voff), "v"(v), "s"(op) : "memory");
}

// G=8 pair-groups per thread, INTERLEAVED: pair p = g*T + t.
// x bytes at 24p (lane stride 24 -> dense), out bytes at 16p (dense).
// Rolling depth-2 pipeline, exact vmcnt ledger (same as verified R5 ledger):
//  P: g0, x2, g1, x3 | b0: st0,g2,x4 | b1: st1,g3,x5 | b2: st2,g4,x6
//  b3: st3,g5,x7 | b4: st4,g6 | b5: st5,g7 | b6: st6 | b7: st7
#define XSTRIDE 6000000u    // T * 24 bytes
#define OSTRIDE 4000000u    // T * 16 bytes

__global__ __launch_bounds__(256, 4) void hashgrid_fwd(
    const float* __restrict__ x,
    const float* __restrict__ emb,
    float* __restrict__ out,
    int nthreads)
{
    int t = blockIdx.x * blockDim.x + threadIdx.x;
    if (t >= nthreads) return;

    uint32_t vx = (uint32_t)t * 24u;    // x byte offset of pair (g=0, t)
    uint32_t vo = (uint32_t)t * 16u;    // out byte offset of pair (g=0, t)

    f2 xA0, xA1, xA2, xB0, xB1, xB2;
    f2 eA[16], eB[16];
    float frA[6], frB[6];
    f4 sv;

    // ---- prologue ----
    xload(xA0, xA1, xA2, vx,            x);      // x(0)
    xload(xB0, xB1, xB2, vx + XSTRIDE,  x);      // x(1)
    WAITV(0);
    hash_issue(xA0, xA1, xA2, frA, eA, emb);     // g0
    xload(xA0, xA1, xA2, vx + 2*XSTRIDE, x);     // x2
    hash_issue(xB0, xB1, xB2, frB, eB, emb);     // g1
    xload(xB0, xB1, xB2, vx + 3*XSTRIDE, x);     // x3
    // outstanding: g0(16), x2(3), g1(16), x3(3)

    // ---- body 0 (A) ----
    WAITV(22);                                   // g0 done (x2,g1,x3 newer)
    consume2(eA, frA, sv);
    store4(vo, out, sv);                         // st0
    WAITV(20);                                   // x2 done (g1,x3,st0)
    hash_issue(xA0, xA1, xA2, frA, eA, emb);     // g2
    xload(xA0, xA1, xA2, vx + 4*XSTRIDE, x);     // x4

    // ---- body 1 (B) ----
    WAITV(23);                                   // g1 done (x3,st0,g2,x4)
    consume2(eB, frB, sv);
    store4(vo + OSTRIDE, out, sv);               // st1
    WAITV(21);                                   // x3 done (st0,g2,x4,st1)
    hash_issue(xB0, xB1, xB2, frB, eB, emb);     // g3
    xload(xB0, xB1, xB2, vx + 5*XSTRIDE, x);     // x5

    // ---- body 2 (A) ----
    WAITV(23);                                   // g2 done (x4,st1,g3,x5)
    consume2(eA, frA, sv);
    store4(vo + 2*OSTRIDE, out, sv);             // st2
    WAITV(21);                                   // x4 done (st1,g3,x5,st2)
    hash_issue(xA0, xA1, xA2, frA, eA, emb);     // g4
    xload(xA0, xA1, xA2, vx + 6*XSTRIDE, x);     // x6

    // ---- body 3 (B) ----
    WAITV(23);                                   // g3 done (x5,st2,g4,x6)
    consume2(eB, frB, sv);
    store4(vo + 3*OSTRIDE, out, sv);             // st3
    WAITV(21);                                   // x5 done (st2,g4,x6,st3)
    hash_issue(xB0, xB1, xB2, frB, eB, emb);     // g5
    xload(xB0, xB1, xB2, vx + 7*XSTRIDE, x);     // x7

    // ---- body 4 (A) ----
    WAITV(23);                                   // g4 done (x6,st3,g5,x7)
    consume2(eA, frA, sv);
    store4(vo + 4*OSTRIDE, out, sv);             // st4
    WAITV(21);                                   // x6 done (st3,g5,x7,st4)
    hash_issue(xA0, xA1, xA2, frA, eA, emb);     // g6 (no x prefetch)

    // ---- body 5 (B) ----
    WAITV(20);                                   // g5 done (x7,st4,g6)
    consume2(eB, frB, sv);
    store4(vo + 5*OSTRIDE, out, sv);             // st5
    WAITV(18);                                   // x7 done (st4,g6,st5)
    hash_issue(xB0, xB1, xB2, frB, eB, emb);     // g7

    // ---- body 6 (A) ----
    WAITV(17);                                   // g6 done (st5,g7)
    consume2(eA, frA, sv);
    store4(vo + 6*OSTRIDE, out, sv);             // st6

    // ---- body 7 (B) ----
    WAITV(1);                                    // g7 done (st6)
    consume2(eB, frB, sv);
    store4(vo + 7*OSTRIDE, out, sv);             // st7
}

// safety net for leftover points (not hit at N=4M with T=250K, G=8)
__global__ void hashgrid_tail(const float* __restrict__ x,
                              const float* __restrict__ emb,
                              float* __restrict__ out,
                              int start, int npts)
{
    int p = start + blockIdx.x * blockDim.x + threadIdx.x;
    if (p >= npts) return;
    uint32_t o[8]; float fr[3];
    hash_point(x[3 * p], x[3 * p + 1], x[3 * p + 2], o, fr);
    const f2* ev = reinterpret_cast<const f2*>(emb);
    float wxa = 1.f - fr[0], wxb = fr[0];
    float wya = 1.f - fr[1], wyb = fr[1];
    float wza = 1.f - fr[2], wzb = fr[2];
    float s0 = 0.f, s1 = 0.f;
    #pragma unroll
    for (int n = 0; n < 8; ++n) {
        float w = (((n & 1) ? wxb : wxa) * ((n & 2) ? wyb : wya))
                  * ((n & 4) ? wzb : wza);
        f2 e = ev[o[n] >> 3];
        s0 = fmaf(e.x, w, s0);
        s1 = fmaf(e.y, w, s1);
    }
    out[2 * p]     = s0;
    out[2 * p + 1] = s1;
}

extern "C" void kernel_launch(void* const* d_in, const int* in_sizes, int n_in,
                              void* d_out, int out_size, void* d_ws, size_t ws_size,
                              hipStream_t stream) {
    const float* x   = (const float*)d_in[0];   // N*3
    const float* emb = (const float*)d_in[1];   // H*2
    float* out = (float*)d_out;                 // N*2

    int npts = in_sizes[0] / 3;                 // 4,000,000
    const int T = 250000;                       // threads (== XSTRIDE/24)
    const int G = 8;                            // pair-groups per thread
    int block = 256;
    int grid = (T + block - 1) / block;         // 977

    hashgrid_fwd<<<grid, block, 0, stream>>>(x, emb, out, T);

    int done = 2 * T * G;                       // 4,000,000
    int rem = npts - done;
    if (rem > 0) {
        int tg = (rem + 255) / 256;
        hashgrid_tail<<<tg, 256, 0, stream>>>(x, emb, out, done, npts);
    }
}

// Round 7
// 99.059 us; speedup vs baseline: 1.5154x; 1.0546x over previous
//
#include <hip/hip_runtime.h>
#include <stdint.h>

#define HASH_MASK 524287u        // HASHMAP_SIZE - 1 (2^19)
#define PRIME1 2654435761u
#define PRIME2 805459861u
#define RES 128.0f

typedef float f4 __attribute__((ext_vector_type(4)));
typedef float f2 __attribute__((ext_vector_type(2)));

// wait until at most N vmem ops outstanding, then hard scheduling fence so
// consumers cannot hoist above the wait. Compiler-inserted vmem ops are
// always SAFE w.r.t. these constants: ops older than a gather retire first;
// ops newer only make the wait stricter.
#define WAITV_(N) asm volatile("s_waitcnt vmcnt(" #N ")" ::: "memory")
#define WAITV(N) do { WAITV_(N); __builtin_amdgcn_sched_barrier(0); } while (0)

// 2 points per thread, one-shot burst. Parity-paired gathers:
//   x-dim prime is 1, so the x-low/x-high corner pair has entry indices
//   {h, (ix+1)^hyz}; when ix is even that is {h, h^1} = one aligned 16B block.
//   A = dwordx4 at (h&~1)<<3  -> always contains the x-low entry (h&1 selects)
//   B = dwordx2 at x-high     -> same 64B line as A when ix even (MSHR merge)
// Distinct lines/point: 8 -> avg 6. Instruction count unchanged (8/point).
__global__ __launch_bounds__(256) void hashgrid_fwd(
    const float* __restrict__ x,    // N*3 fp32
    const float* __restrict__ emb,  // H*2 fp32
    float* __restrict__ out,        // N*2 fp32
    int nthreads)                   // N/2
{
    int t = blockIdx.x * blockDim.x + threadIdx.x;
    if (t >= nthreads) return;

    // 2 points = 6 floats = 3 coalesced 8B loads, lane stride 24B (dense).
    // nt: keep the streaming x data from evicting the L2-resident table.
    const f2* xv = reinterpret_cast<const f2*>(x) + (size_t)t * 3;
    f2 q0 = __builtin_nontemporal_load(xv);
    f2 q1 = __builtin_nontemporal_load(xv + 1);
    f2 q2 = __builtin_nontemporal_load(xv + 2);

    const float P[2][3] = {{q0.x, q0.y, q1.x}, {q1.y, q2.x, q2.y}};

    uint32_t h0v[8];     // x-low corner entry index, [4*p + m]
    uint32_t offB[8];    // byte offset of x-high corner entry
    float fr[6];

    #pragma unroll
    for (int p = 0; p < 2; ++p) {
        float fx = P[p][0] * RES, fy = P[p][1] * RES, fz = P[p][2] * RES;
        float flx = floorf(fx), fly = floorf(fy), flz = floorf(fz);
        int ix = (int)flx, iy = (int)fly, iz = (int)flz;
        fr[3*p+0] = fx - flx; fr[3*p+1] = fy - fly; fr[3*p+2] = fz - flz;

        uint32_t hx_lo = (uint32_t)ix;           // prime = 1
        uint32_t hx_hi = hx_lo + 1u;
        uint32_t h1a = (uint32_t)iy * PRIME1, h1b = h1a + PRIME1;
        uint32_t h2a = (uint32_t)iz * PRIME2, h2b = h2a + PRIME2;

        #pragma unroll
        for (int m = 0; m < 4; ++m) {            // m: (y,z) combo, bit0=y bit1=z
            uint32_t hyz = ((m & 1) ? h1b : h1a) ^ ((m & 2) ? h2b : h2a);
            h0v[4*p+m]  = (hx_lo ^ hyz) & HASH_MASK;
            offB[4*p+m] = ((hx_hi ^ hyz) & HASH_MASK) << 3;
        }
    }

    // issue all 16 gathers (A,B interleaved so B merges into A's MSHR line
    // when ix even). asm: issue order fixed, results forced live.
    f4 vA[8]; f2 vB[8];
    #pragma unroll
    for (int i = 0; i < 8; ++i) {
        uint32_t offA = (h0v[i] & ~1u) << 3;     // aligned 16B block {E, E+1}
        asm volatile("global_load_dwordx4 %0, %1, %2"
                     : "=v"(vA[i]) : "v"(offA), "s"(emb));
        asm volatile("global_load_dwordx2 %0, %1, %2"
                     : "=v"(vB[i]) : "v"(offB[i]), "s"(emb));
    }

    // staged consumption: pt0's 8 ops done when 8 newer (pt1's) remain.
    float s[4];
    #pragma unroll
    for (int p = 0; p < 2; ++p) {
        if (p == 0) { WAITV(8); } else { WAITV(0); }
        float wxa = 1.f - fr[3*p+0], wxb = fr[3*p+0];
        float wya = 1.f - fr[3*p+1], wyb = fr[3*p+1];
        float wza = 1.f - fr[3*p+2], wzb = fr[3*p+2];
        float a0 = 0.f, a1 = 0.f;
        #pragma unroll
        for (int m = 0; m < 4; ++m) {
            f4 A = vA[4*p+m];
            f2 B = vB[4*p+m];
            bool hi = (h0v[4*p+m] & 1u) != 0;    // which half of A is entry h
            float elx = hi ? A.z : A.x;
            float ely = hi ? A.w : A.y;
            // contribution = wyz * (e_lo*wxa + e_hi*wxb), e_hi = B always
            float wyz = ((m & 1) ? wyb : wya) * ((m & 2) ? wzb : wza);
            float gx = fmaf(elx, wxa, B.x * wxb);
            float gy = fmaf(ely, wxa, B.y * wxb);
            a0 = fmaf(wyz, gx, a0);
            a1 = fmaf(wyz, gy, a1);
        }
        s[2*p+0] = a0; s[2*p+1] = a1;
    }

    // 2 points * float2 = 1 coalesced 16B store (nt: pure stream)
    f4 o = {s[0], s[1], s[2], s[3]};
    __builtin_nontemporal_store(o, reinterpret_cast<f4*>(out) + t);
}

// safety net for npts % 2 != 0 (not hit at N=4M)
__global__ void hashgrid_tail(const float* __restrict__ x,
                              const float* __restrict__ emb,
                              float* __restrict__ out,
                              int start, int npts)
{
    int p = start + blockIdx.x * blockDim.x + threadIdx.x;
    if (p >= npts) return;
    float fx = x[3*p] * RES, fy = x[3*p+1] * RES, fz = x[3*p+2] * RES;
    float flx = floorf(fx), fly = floorf(fy), flz = floorf(fz);
    int ix = (int)flx, iy = (int)fly, iz = (int)flz;
    float tx = fx - flx, ty = fy - fly, tz = fz - flz;
    uint32_t h0a = (uint32_t)ix,          h0b = h0a + 1u;
    uint32_t h1a = (uint32_t)iy * PRIME1, h1b = h1a + PRIME1;
    uint32_t h2a = (uint32_t)iz * PRIME2, h2b = h2a + PRIME2;
    const f2* ev = reinterpret_cast<const f2*>(emb);
    float s0 = 0.f, s1 = 0.f;
    #pragma unroll
    for (int n = 0; n < 8; ++n) {
        uint32_t h = ((n & 1) ? h0b : h0a)
                   ^ ((n & 2) ? h1b : h1a)
                   ^ ((n & 4) ? h2b : h2a);
        float w = (((n & 1) ? tx : 1.f - tx) * ((n & 2) ? ty : 1.f - ty))
                  * ((n & 4) ? tz : 1.f - tz);
        f2 e = ev[h & HASH_MASK];
        s0 = fmaf(e.x, w, s0);
        s1 = fmaf(e.y, w, s1);
    }
    out[2*p]   = s0;
    out[2*p+1] = s1;
}

extern "C" void kernel_launch(void* const* d_in, const int* in_sizes, int n_in,
                              void* d_out, int out_size, void* d_ws, size_t ws_size,
                              hipStream_t stream) {
    const float* x   = (const float*)d_in[0];   // N*3
    const float* emb = (const float*)d_in[1];   // H*2
    float* out = (float*)d_out;                 // N*2

    int npts = in_sizes[0] / 3;                 // 4,000,000
    int nthreads = npts / 2;                    // 2,000,000
    int block = 256;
    int grid = (nthreads + block - 1) / block;  // 7813

    hashgrid_fwd<<<grid, block, 0, stream>>>(x, emb, out, nthreads);

    int done = nthreads * 2;
    int rem = npts - done;
    if (rem > 0) {
        int tg = (rem + 255) / 256;
        hashgrid_tail<<<tg, 256, 0, stream>>>(x, emb, out, done, npts);
    }
}